// Round 6
// baseline (370.206 us; speedup 1.0000x reference)
//
#include <hip/hip_runtime.h>
#include <hip/hip_bf16.h>
#include <cstdint>
#include <cstddef>

#define ALPHA_ 0.1f

static inline int cdiv(int a, int b) { return (a + b - 1) / b; }

typedef __attribute__((ext_vector_type(8))) short short8;
typedef __attribute__((ext_vector_type(4))) short short4v;
typedef __attribute__((ext_vector_type(4))) float float4v;

__device__ __forceinline__ void gload_lds16(const void* g, void* l) {
  __builtin_amdgcn_global_load_lds((const __attribute__((address_space(1))) unsigned int*)g,
                                   (__attribute__((address_space(3))) unsigned int*)l,
                                   16, 0, 0);
}

// ---------------- WtT builder: tiled + swizzled bf16 transpose of W (K x 128) ----------------
// Tile s covers k in [s*64,(s+1)*64). Element (k,c) stored at
//   s*8192 + c*64 + ((j ^ (c&7))<<3) + e   where j=(k>>3)&7, e=k&7.  (zero-padded k>=K)
__global__ __launch_bounds__(256) void make_wtT(const float* __restrict__ W,
                                                __hip_bfloat16* __restrict__ WtT,
                                                int K)
{
  __shared__ float tile[64][33];
  const int t  = threadIdx.x;
  const int k0 = blockIdx.x * 64;
  const int c0 = blockIdx.y * 32;
  {
    const int cc = t & 31;
    const int kr = t >> 5;
#pragma unroll
    for (int pass = 0; pass < 8; ++pass) {
      int k = k0 + kr + pass * 8;
      float v = (k < K) ? W[(size_t)k * 128 + (c0 + cc)] : 0.f;
      tile[kr + pass * 8][cc] = v;
    }
  }
  __syncthreads();
  {
    const int kk = t & 63;
    const int cl = t >> 6;
    const int s  = k0 >> 6;
    const int j  = kk >> 3, e = kk & 7;
#pragma unroll
    for (int pass = 0; pass < 8; ++pass) {
      int c = c0 + cl + pass * 4;
      size_t addr = (size_t)s * 8192 + (size_t)c * 64 + (size_t)(((j ^ (c & 7)) << 3) + e);
      WtT[addr] = __float2bfloat16(tile[kk][cl + pass * 4]);
    }
  }
}

// ---------------- init GEMM: A reg-pipelined (depth 3), W LDS dbuf via DMA, counted vmcnt ----
// Block: 512 thr = 8 waves; out tile 128 rows x 128 cols; BK=64; split-K=KSPLIT.
// A rows never cross waves -> each lane loads exactly its MFMA B-fragment source (no LDS for A).
// Raw s_barrier + s_waitcnt vmcnt(4): retires {A(s+1), W(s+1)}, keeps A(s+2) in flight.
// NOTE: requires every K-segment to have >= 2 steps (St/KSPLIT >= 2) for the prologue vmcnt(8).
template<int KSPLIT>
__global__ __launch_bounds__(512, 4) void init_mfma_pipe(
    const float* __restrict__ Am, const __hip_bfloat16* __restrict__ Wtm, int Nm_, int nbm,
    const float* __restrict__ Ad, const __hip_bfloat16* __restrict__ Wtd, int Nd_, int Kpd,
    float* __restrict__ p0, float* __restrict__ p1, float* __restrict__ p2,
    float* __restrict__ p3, float* __restrict__ p4)
{
  __shared__ __align__(16) __hip_bfloat16 lds_w[2][128 * 64];   // 32 KB total

  const int t    = threadIdx.x;
  const int lane = t & 63;
  const int wv   = t >> 6;

  const int nb_total = gridDim.x / KSPLIT;
  int mb    = blockIdx.x % nb_total;
  int chunk = blockIdx.x / nb_total;

  const float* A; const __hip_bfloat16* Wt; int N, K, Kpad, rowoff, rb;
  if (mb < nbm) { A = Am; Wt = Wtm; N = Nm_; K = Nm_; Kpad = Nm_; rowoff = 0;   rb = mb; }
  else          { A = Ad; Wt = Wtd; N = Nd_; K = Nd_; Kpad = Kpd; rowoff = Nm_; rb = mb - nbm; }

  float* Cp = (chunk == 0) ? p0 : (chunk == 1) ? p1 : (chunk == 2) ? p2 : (chunk == 3) ? p3 : p4;

  const int St = Kpad / 64;
  const int s0 = (int)(((long)St * chunk) / KSPLIT);
  const int s1 = (int)(((long)St * (chunk + 1)) / KSPLIT);

  // per-lane A source: row = rb*128 + wv*16 + (lane&15), k base = (lane>>4)*8
  const int rloc = lane & 15;
  const int kg8  = (lane >> 4) * 8;
  const int row_g0 = rb * 128;
  int r  = row_g0 + wv * 16 + rloc;
  int ra = (r < N) ? r : (N - 1);
  const float* abase = A + (size_t)ra * K;
  const int kclamp = K - 4;

  // W fragment read offsets (swizzled; verified layout)
  int w_roff[2][8];
#pragma unroll
  for (int h = 0; h < 2; ++h) {
    int j = h * 4 + (lane >> 4);
#pragma unroll
    for (int mt = 0; mt < 8; ++mt) {
      int col = mt * 16 + rloc;
      w_roff[h][mt] = col * 64 + ((j ^ (col & 7)) << 3);
    }
  }

  float4v acc[8];
#pragma unroll
  for (int mt = 0; mt < 8; ++mt) acc[mt] = (float4v){0.f, 0.f, 0.f, 0.f};

  const char* wt_bytes = (const char*)Wt;

  // A pipeline registers: step s (cur), s+1, s+2
  float4v A0a, A0b, A0c, A0d, A1a, A1b, A1c, A1d, A2a, A2b, A2c, A2d;

#define LOADA(s_, Ra, Rb, Rc, Rd)                                                \
  {                                                                              \
    int kb = (s_) * 64 + kg8;                                                    \
    int k0_ = kb      > kclamp ? kclamp : kb;                                    \
    int k1_ = kb + 4  > kclamp ? kclamp : kb + 4;                                \
    int k2_ = kb + 32 > kclamp ? kclamp : kb + 32;                               \
    int k3_ = kb + 36 > kclamp ? kclamp : kb + 36;                               \
    Ra = *(const float4v*)(abase + k0_);                                         \
    Rb = *(const float4v*)(abase + k1_);                                         \
    Rc = *(const float4v*)(abase + k2_);                                         \
    Rd = *(const float4v*)(abase + k3_);                                         \
  }

#define ISSUE_W(s_, bb_)                                                         \
  {                                                                              \
    const char* gs_ = wt_bytes + (size_t)(s_) * 16384;                           \
    gload_lds16(gs_ + (size_t)(wv * 64 + lane) * 16,                             \
                &lds_w[bb_][(size_t)(wv * 64) * 8]);                             \
    gload_lds16(gs_ + (size_t)(512 + wv * 64 + lane) * 16,                       \
                &lds_w[bb_][(size_t)(512 + wv * 64) * 8]);                       \
  }

  // prologue: W(s0) -> buf0; A(s0), A(s0+1) into regs
  ISSUE_W(s0, 0);
  LOADA(s0, A0a, A0b, A0c, A0d);
  if (s0 + 1 < s1) LOADA(s0 + 1, A1a, A1b, A1c, A1d);
  asm volatile("s_waitcnt vmcnt(8)" ::: "memory");   // retires W(s0); keeps A0/A1 in flight
  __builtin_amdgcn_sched_barrier(0);
  __builtin_amdgcn_s_barrier();
  __builtin_amdgcn_sched_barrier(0);

  int bb = 0;
  for (int s = s0; s < s1; ++s) {
    if (s + 1 < s1) ISSUE_W(s + 1, bb ^ 1);          // W first
    if (s + 2 < s1) LOADA(s + 2, A2a, A2b, A2c, A2d); // then A (ordering matters for vmcnt(4))

    // compute step s: cvt A0 regs -> 2 bf16 fragments, MFMA against LDS W
    union { short8 v; __hip_bfloat16 h[8]; } f0, f1;
    f0.h[0] = __float2bfloat16(A0a.x); f0.h[1] = __float2bfloat16(A0a.y);
    f0.h[2] = __float2bfloat16(A0a.z); f0.h[3] = __float2bfloat16(A0a.w);
    f0.h[4] = __float2bfloat16(A0b.x); f0.h[5] = __float2bfloat16(A0b.y);
    f0.h[6] = __float2bfloat16(A0b.z); f0.h[7] = __float2bfloat16(A0b.w);
    f1.h[0] = __float2bfloat16(A0c.x); f1.h[1] = __float2bfloat16(A0c.y);
    f1.h[2] = __float2bfloat16(A0c.z); f1.h[3] = __float2bfloat16(A0c.w);
    f1.h[4] = __float2bfloat16(A0d.x); f1.h[5] = __float2bfloat16(A0d.y);
    f1.h[6] = __float2bfloat16(A0d.z); f1.h[7] = __float2bfloat16(A0d.w);

    const __hip_bfloat16* lw = lds_w[bb];
#pragma unroll
    for (int mt = 0; mt < 8; ++mt) {
      short8 wfrag = *(const short8*)(lw + w_roff[0][mt]);
      acc[mt] = __builtin_amdgcn_mfma_f32_16x16x32_bf16(wfrag, f0.v, acc[mt], 0, 0, 0);
    }
#pragma unroll
    for (int mt = 0; mt < 8; ++mt) {
      short8 wfrag = *(const short8*)(lw + w_roff[1][mt]);
      acc[mt] = __builtin_amdgcn_mfma_f32_16x16x32_bf16(wfrag, f1.v, acc[mt], 0, 0, 0);
    }

    // rotate A pipeline
    A0a = A1a; A0b = A1b; A0c = A1c; A0d = A1d;
    A1a = A2a; A1b = A2b; A1c = A2c; A1d = A2d;

    // counted drain: retire own {A(s+1), W(s+1)}, keep A(s+2) in flight across barrier
    asm volatile("s_waitcnt vmcnt(4)" ::: "memory");
    __builtin_amdgcn_sched_barrier(0);
    __builtin_amdgcn_s_barrier();
    __builtin_amdgcn_sched_barrier(0);
    bb ^= 1;
  }

  if (r < N) {
    float* dst = Cp + (size_t)(rowoff + r) * 128 + (lane >> 4) * 4;
#pragma unroll
    for (int mt = 0; mt < 8; ++mt)
      *(float4v*)(dst + mt * 16) = acc[mt];
  }
#undef LOADA
#undef ISSUE_W
}

// sum 5 partials; write init AND both state copies (aliasing OK: per-thread read-then-write)
__global__ __launch_bounds__(256) void combine5(
    const float4v* a, const float4v* b, const float4v* c, const float4v* d, const float4v* e,
    float4v* o_init, float4v* o_s0, float4v* o_s1, int n4)
{
  int i = blockIdx.x * 256 + threadIdx.x;
  if (i >= n4) return;
  float4v x = a[i], y = b[i], z = c[i], u = d[i], v = e[i];
  float4v s = (float4v){x.x+y.x+z.x+u.x+v.x, x.y+y.y+z.y+u.y+v.y,
                        x.z+y.z+z.z+u.z+v.z, x.w+y.w+z.w+u.w+v.w};
  o_init[i] = s; o_s0[i] = s; o_s1[i] = s;
}

// ---------------- unified gather, fully unrolled over P and L ----------------
template<int L, int PP>
__device__ __forceinline__ float gath(const float* __restrict__ sect, const int* __restrict__ paths,
                                      const float* __restrict__ pw, int n, int N, int d)
{
  float pwv[L];
#pragma unroll
  for (int l = 0; l < L; ++l) pwv[l] = pw[l * 128 + d];
  float acc = 0.f;
  const int* ip0 = paths + (size_t)n * L;
#pragma unroll
  for (int p = 0; p < PP; ++p) {
    const int* ip = ip0 + (size_t)p * N * L;   // wave-uniform -> scalar loads
    int idx[L];
#pragma unroll
    for (int l = 0; l < L; ++l) idx[l] = ip[l];
#pragma unroll
    for (int l = 0; l < L; ++l)
      acc = fmaf(pwv[l], sect[(size_t)idx[l] * 128 + d], acc);
  }
  return acc;
}

template<int LMM, int LMD, int PP>
__global__ __launch_bounds__(256) void gather_all(
    const float* __restrict__ state,
    const int* __restrict__ paths_mm, const int* __restrict__ paths_dd, const int* __restrict__ paths_md,
    const float* __restrict__ pw1l, const float* __restrict__ pw2l,
    float* __restrict__ r, int Nm, int Nd)
{
  const int d = threadIdx.x & 127;
  const int nsub = threadIdx.x >> 7;
  const int g = blockIdx.x * 2 + nsub;
  const int Nt = Nm + Nd;
  if (g >= 2 * Nt) return;
  float acc;
  if (g < Nm)
    acc = gath<LMM, PP>(state, paths_mm, pw1l, g, Nm, d);
  else if (g < Nt)
    acc = gath<LMM, PP>(state + (size_t)Nm * 128, paths_dd, pw1l, g - Nm, Nd, d);
  else
    acc = gath<LMD, PP>(state + (size_t)Nt * 128, paths_md, pw2l, g - Nt, Nt, d);
  r[(size_t)g * 128 + d] = acc * (1.0f / (float)PP);
}

// runtime fallback
__global__ __launch_bounds__(256) void gather_einsum_rt(
    const float* __restrict__ feats, const int* __restrict__ paths,
    const float* __restrict__ pw, float* __restrict__ r, int N, int P, int L)
{
  const int d = threadIdx.x & 127;
  const int n = blockIdx.x * 2 + (threadIdx.x >> 7);
  if (n >= N) return;
  float acc = 0.f;
  for (int p = 0; p < P; ++p) {
    const int* ip = paths + ((size_t)p * N + n) * L;
    for (int l = 0; l < L; ++l)
      acc = fmaf(pw[l * 128 + d], feats[(size_t)ip[l] * 128 + d], acc);
  }
  r[(size_t)n * 128 + d] = acc * (1.0f / (float)P);
}

// ---------------- fc layer: compile-time K=128, ILP via unroll ----------------
template<int TR>
__global__ __launch_bounds__(256) void fc_all(
    const float* __restrict__ Rm, const float* __restrict__ W,
    const float* __restrict__ initb, float* __restrict__ state, int Ntot, int Nt)
{
  const int col = threadIdx.x & 127;
  const int rh  = __builtin_amdgcn_readfirstlane((int)(threadIdx.x >> 7));
  const int row0 = blockIdx.x * (2 * TR) + rh * TR;
  const float* arow[TR];
#pragma unroll
  for (int r = 0; r < TR; ++r) {
    int rr = row0 + r; if (rr > Ntot - 1) rr = Ntot - 1;
    arow[r] = Rm + (size_t)rr * 128;
  }
  float acc[TR];
#pragma unroll
  for (int r = 0; r < TR; ++r) acc[r] = 0.f;
#pragma unroll 4
  for (int k = 0; k < 128; k += 8) {
    float w[8];
#pragma unroll
    for (int kk = 0; kk < 8; ++kk) w[kk] = W[(size_t)(k + kk) * 128 + col];
#pragma unroll
    for (int r = 0; r < TR; ++r) {
      const float* ap = arow[r] + k;
#pragma unroll
      for (int kk = 0; kk < 8; ++kk) acc[r] = fmaf(ap[kk], w[kk], acc[r]);
    }
  }
#pragma unroll
  for (int r = 0; r < TR; ++r) {
    int rr = row0 + r;
    if (rr < Ntot) {
      int rbase = (rr < Nt) ? rr : rr - Nt;
      state[(size_t)rr * 128 + col] =
          ALPHA_ * initb[(size_t)rbase * 128 + col] + (1.f - ALPHA_) * fmaxf(acc[r], 0.f);
    }
  }
}

// MLP collapse (ILP-4)
__global__ void collapse1(const float* __restrict__ W0, const float* __restrict__ b0,
                          const float* __restrict__ W1, const float* __restrict__ b1,
                          float* __restrict__ w01, float* __restrict__ b01,
                          int E, int K0, int H1)
{
  int row = blockIdx.x; int c = threadIdx.x;
  if (c >= H1) return;
  const float* src; float base;
  if (row < E) { src = W0 + (size_t)row * K0; base = 0.f; }
  else         { src = b0; base = b1[c]; }
  float a0 = 0.f, a1 = 0.f, a2 = 0.f, a3 = 0.f;
#pragma unroll 4
  for (int k = 0; k < K0; k += 4) {
    a0 = fmaf(src[k + 0], W1[(size_t)(k + 0) * H1 + c], a0);
    a1 = fmaf(src[k + 1], W1[(size_t)(k + 1) * H1 + c], a1);
    a2 = fmaf(src[k + 2], W1[(size_t)(k + 2) * H1 + c], a2);
    a3 = fmaf(src[k + 3], W1[(size_t)(k + 3) * H1 + c], a3);
  }
  float acc = base + ((a0 + a1) + (a2 + a3));
  if (row < E) w01[(size_t)row * H1 + c] = acc; else b01[c] = acc;
}

__global__ void collapse2(const float* __restrict__ w01, const float* __restrict__ b01,
                          const float* __restrict__ W2, const float* __restrict__ b2,
                          float* __restrict__ w512, float* __restrict__ csc,
                          int E, int H1)
{
  int i = blockIdx.x * blockDim.x + threadIdx.x;
  if (i < E) {
    float a0 = 0.f, a1 = 0.f, a2 = 0.f, a3 = 0.f;
    for (int j = 0; j < H1; j += 4) {
      a0 = fmaf(w01[(size_t)i * H1 + j + 0], W2[j + 0], a0);
      a1 = fmaf(w01[(size_t)i * H1 + j + 1], W2[j + 1], a1);
      a2 = fmaf(w01[(size_t)i * H1 + j + 2], W2[j + 2], a2);
      a3 = fmaf(w01[(size_t)i * H1 + j + 3], W2[j + 3], a3);
    }
    w512[i] = (a0 + a1) + (a2 + a3);
  } else if (i == E) {
    float a = b2[0];
    for (int j = 0; j < H1; ++j) a = fmaf(b01[j], W2[j], a);
    csc[0] = a;
  }
}

__global__ __launch_bounds__(256) void node_partial(
    const float* __restrict__ Fmm, const float* __restrict__ Fdd, const float* __restrict__ Fmd,
    const float* __restrict__ w512, float* __restrict__ uv, int Nm, int Nt)
{
  int gid = blockIdx.x * blockDim.x + threadIdx.x;
  int wid = gid >> 6;
  int lane = threadIdx.x & 63;
  if (wid >= Nt) return;
  bool isM = wid < Nm;
  const float* X = isM ? (Fmm + (size_t)wid * 128) : (Fdd + (size_t)(wid - Nm) * 128);
  const float* Y = Fmd + (size_t)wid * 128;
  const float* w1 = w512 + (isM ? 0 : 256);
  const float* w2 = w1 + 128;
  float s = fmaf(X[lane], w1[lane], 0.f);
  s = fmaf(X[lane + 64], w1[lane + 64], s);
  s = fmaf(Y[lane], w2[lane], s);
  s = fmaf(Y[lane + 64], w2[lane + 64], s);
#pragma unroll
  for (int off = 32; off > 0; off >>= 1) s += __shfl_down(s, off);
  if (lane == 0) uv[wid] = s;
}

__global__ __launch_bounds__(256) void score_kernel(
    const int* __restrict__ samples, const float* __restrict__ u, const float* __restrict__ v,
    const float* __restrict__ csc, float* __restrict__ out, int S)
{
  int s = blockIdx.x * blockDim.x + threadIdx.x;
  if (s >= S) return;
  const int2 ij = ((const int2*)samples)[s];
  float x = u[ij.x] + v[ij.y] + csc[0];
  out[s] = 1.0f / (1.0f + expf(-x));
}

extern "C" void kernel_launch(void* const* d_in, const int* in_sizes, int n_in,
                              void* d_out, int out_size, void* d_ws, size_t ws_size,
                              hipStream_t stream)
{
  const int*   paths_mm = (const int*)d_in[0];
  const int*   paths_dd = (const int*)d_in[1];
  const int*   paths_md = (const int*)d_in[2];
  const float* miRNA    = (const float*)d_in[3];
  const float* disease  = (const float*)d_in[4];
  const int*   samples  = (const int*)d_in[5];
  const float* Wm  = (const float*)d_in[6];
  const float* Wd  = (const float*)d_in[7];
  const float* pw1 = (const float*)d_in[8];
  const float* pw2 = (const float*)d_in[9];
  const float* fcW = (const float*)d_in[10];
  const float* W0  = (const float*)d_in[11];
  const float* b0  = (const float*)d_in[12];
  const float* W1  = (const float*)d_in[13];
  const float* b1  = (const float*)d_in[14];
  const float* W2  = (const float*)d_in[15];
  const float* b2  = (const float*)d_in[16];

  const int D  = 128;
  const int Nm = in_sizes[6] / D;
  const int Nd = in_sizes[7] / D;
  const int Nt = Nm + Nd;
  const int S  = in_sizes[5] / 2;
  const int layers = in_sizes[10] / (D * D);
  const int L1 = in_sizes[8] / (layers * D);
  const int L2 = in_sizes[9] / (layers * D);
  const int P  = in_sizes[0] / (Nm * L1);
  const int E  = 4 * D;
  const int K0 = in_sizes[12];
  const int H1 = in_sizes[14];
  const int Kpm = cdiv(Nm, 64) * 64;   // 8000
  const int Kpd = cdiv(Nd, 64) * 64;   // 6016

  float* out = (float*)d_out;
  float* ws  = (float*)d_ws;
  size_t off = 0;
  float* init  = ws + off; off += (size_t)Nt * D;       // summed init feats (m;d)
  float* state = ws + off; off += (size_t)2 * Nt * D;   // [mm(Nm); dd(Nd); md(Nt)]
  float* bufR  = ws + off; off += (size_t)2 * Nt * D;   // gather output
  float* w01   = ws + off; off += (size_t)E * H1;
  float* b01   = ws + off; off += H1;
  float* w512  = ws + off; off += E;
  float* csc   = ws + off; off += 1;
  float* uv    = ws + off; off += Nt;
  __hip_bfloat16* WtTm = (__hip_bfloat16*)(ws + off); off += (size_t)D * Kpm / 2;
  __hip_bfloat16* WtTd = (__hip_bfloat16*)(ws + off); off += (size_t)D * Kpd / 2;
  (void)ws_size; (void)n_in; (void)out_size;

  // 1. tiled+swizzled bf16 weight transposes (coalesced via LDS tile transpose)
  {
    dim3 g1(Kpm / 64, 4); make_wtT<<<g1, 256, 0, stream>>>(Wm, WtTm, Nm);
    dim3 g2(Kpd / 64, 4); make_wtT<<<g2, 256, 0, stream>>>(Wd, WtTd, Nd);
  }

  // 2. MLP collapse (independent of features)
  collapse1<<<E + 1, 64, 0, stream>>>(W0, b0, W1, b1, w01, b01, E, K0, H1);
  collapse2<<<cdiv(E + 1, 256), 256, 0, stream>>>(w01, b01, W2, b2, w512, csc, E, H1);

  // 3. init GEMMs: reg-pipelined A + counted-vmcnt barriers, split-K=5
  {
    constexpr int KSPLIT = 5;   // St/KSPLIT >= 18 steps per segment (prologue needs >=2)
    int nbm = cdiv(Nm, 128), nbd = cdiv(Nd, 128);
    init_mfma_pipe<KSPLIT><<<(nbm + nbd) * KSPLIT, 512, 0, stream>>>(
        miRNA, WtTm, Nm, nbm, disease, WtTd, Nd, Kpd,
        init, state, state + (size_t)Nt * D, bufR, bufR + (size_t)Nt * D);
    int n4 = Nt * D / 4;
    combine5<<<cdiv(n4, 256), 256, 0, stream>>>(
        (const float4v*)init, (const float4v*)state, (const float4v*)(state + (size_t)Nt * D),
        (const float4v*)bufR, (const float4v*)(bufR + (size_t)Nt * D),
        (float4v*)init, (float4v*)state, (float4v*)(state + (size_t)Nt * D), n4);
  }

  // 4. fused path-layer chains
  constexpr int TR = 8;
  for (int l = 0; l < layers; ++l) {
    const float* pw1l = pw1 + (size_t)l * L1 * D;
    const float* pw2l = pw2 + (size_t)l * L2 * D;
    if (L1 == 4 && L2 == 6 && P == 8) {
      gather_all<4, 6, 8><<<Nt, 256, 0, stream>>>(
          state, paths_mm, paths_dd, paths_md, pw1l, pw2l, bufR, Nm, Nd);
    } else {
      gather_einsum_rt<<<cdiv(Nm, 2), 256, 0, stream>>>(state, paths_mm, pw1l, bufR, Nm, P, L1);
      gather_einsum_rt<<<cdiv(Nd, 2), 256, 0, stream>>>(state + (size_t)Nm * D, paths_dd, pw1l,
                                                        bufR + (size_t)Nm * D, Nd, P, L1);
      gather_einsum_rt<<<cdiv(Nt, 2), 256, 0, stream>>>(state + (size_t)Nt * D, paths_md, pw2l,
                                                        bufR + (size_t)Nt * D, Nt, P, L2);
    }
    fc_all<TR><<<cdiv(2 * Nt, 2 * TR), 256, 0, stream>>>(
        bufR, fcW + (size_t)l * D * D, init, state, 2 * Nt, Nt);
  }

  // 5. per-node partial dots + scoring
  node_partial<<<cdiv(Nt * 64, 256), 256, 0, stream>>>(
      state, state + (size_t)Nm * D, state + (size_t)Nt * D, w512, uv, Nm, Nt);
  score_kernel<<<cdiv(S, 256), 256, 0, stream>>>(samples, uv, uv + Nm, csc, out, S);
}

// Round 7
// 350.607 us; speedup vs baseline: 1.0559x; 1.0559x over previous
//
#include <hip/hip_runtime.h>
#include <hip/hip_bf16.h>
#include <cstdint>
#include <cstddef>

#define ALPHA_ 0.1f

static inline int cdiv(int a, int b) { return (a + b - 1) / b; }

typedef __attribute__((ext_vector_type(8))) short short8;
typedef __attribute__((ext_vector_type(4))) short short4v;
typedef __attribute__((ext_vector_type(4))) float float4v;

struct P8 { float* p[8]; };

__device__ __forceinline__ void gload_lds16(const void* g, void* l) {
  __builtin_amdgcn_global_load_lds((const __attribute__((address_space(1))) unsigned int*)g,
                                   (__attribute__((address_space(3))) unsigned int*)l,
                                   16, 0, 0);
}

// ---------------- WtT builder: tile-major bf16 transpose of W (K x 128) ----------------
// k-tile s (32 k values): element (k, c) -> WtT[s*4096 + c*32 + (k - s*32)], zero-pad k>=K.
__global__ __launch_bounds__(256) void make_wtT(const float* __restrict__ W,
                                                __hip_bfloat16* __restrict__ WtT,
                                                int K)
{
  __shared__ float tile[32][129];
  const int t  = threadIdx.x;
  const int s  = blockIdx.x;
  const int k0 = s * 32;
#pragma unroll
  for (int pass = 0; pass < 16; ++pass) {
    int idx = pass * 256 + t;
    int k = idx >> 7, c = idx & 127;
    tile[k][c] = (k0 + k < K) ? W[(size_t)(k0 + k) * 128 + c] : 0.f;
  }
  __syncthreads();
#pragma unroll
  for (int pass = 0; pass < 16; ++pass) {
    int idx = pass * 256 + t;
    int c = idx >> 5, kl = idx & 31;
    WtT[(size_t)s * 4096 + c * 32 + kl] = __float2bfloat16(tile[kl][c]);
  }
}

// ---------------- init GEMM: BM=64, BK=32, 4 waves, 24KB LDS, 6 blocks/CU ----------------
// A: reg-staged (contiguous 128B-run loads) -> LDS [64][32] bf16 (conflict-free, no swizzle).
// W: linear global_load_lds from tile-major WtT -> LDS [128][32] bf16.
// chunk = bid % KSPLIT (XCD-affine W k-slices on round-robin dispatch).
template<int KSPLIT>
__global__ __launch_bounds__(256, 6) void init_mfma2(
    const float* __restrict__ Am, const __hip_bfloat16* __restrict__ Wtm, int Nm_, int nbm,
    const float* __restrict__ Ad, const __hip_bfloat16* __restrict__ Wtd, int Nd_, int Kpd,
    P8 parr)
{
  __shared__ __align__(16) __hip_bfloat16 lds_a[2][64 * 32];    // 2 x 4KB
  __shared__ __align__(16) __hip_bfloat16 lds_w[2][128 * 32];   // 2 x 8KB

  const int t    = threadIdx.x;
  const int lane = t & 63;
  const int wv   = t >> 6;

  const int chunk = blockIdx.x % KSPLIT;
  int mb          = blockIdx.x / KSPLIT;

  const float* A; const __hip_bfloat16* Wt; int N, K, Kpad, rowoff, rb;
  if (mb < nbm) { A = Am; Wt = Wtm; N = Nm_; K = Nm_; Kpad = Nm_; rowoff = 0;   rb = mb; }
  else          { A = Ad; Wt = Wtd; N = Nd_; K = Nd_; Kpad = Kpd; rowoff = Nm_; rb = mb - nbm; }

  float* Cp = parr.p[chunk];

  const int St = Kpad / 32;
  const int s0 = (int)(((long)St * chunk) / KSPLIT);
  const int s1 = (int)(((long)St * (chunk + 1)) / KSPLIT);

  // ---- A staging: instr i stages row wv*16 + i*8 + (lane>>3), floats (lane&7)*4 ----
  const int ld_row = wv * 16 + (lane >> 3);
  const int ld_kf  = (lane & 7) * 4;
  const int row_g0 = rb * 64;
  const float* aptr[2];
  int a_woff[2];   // LDS byte offsets
#pragma unroll
  for (int i = 0; i < 2; ++i) {
    int rg = row_g0 + ld_row + i * 8;
    if (rg > N - 1) rg = N - 1;
    aptr[i] = A + (size_t)rg * K;
    a_woff[i] = (ld_row + i * 8) * 64 + ld_kf * 2;
  }
  const int kclamp = K - 4;

  // ---- fragment byte offsets ----
  const int rloc = lane & 15;
  const int kg   = lane >> 4;
  const int a_roff = (wv * 16 + rloc) * 64 + kg * 16;
  int w_roff[8];
#pragma unroll
  for (int mt = 0; mt < 8; ++mt)
    w_roff[mt] = (mt * 16 + rloc) * 64 + kg * 16;

  float4v acc[8];
#pragma unroll
  for (int mt = 0; mt < 8; ++mt) acc[mt] = (float4v){0.f, 0.f, 0.f, 0.f};

  const char* wt_bytes = (const char*)Wt;
  float4v a_st0, a_st1;

#define STAGE_LOAD(s_, bb_)                                                     \
  {                                                                             \
    int kc0 = (s_) * 32 + ld_kf; if (kc0 > kclamp) kc0 = kclamp;                \
    a_st0 = *(const float4v*)(aptr[0] + kc0);                                   \
    a_st1 = *(const float4v*)(aptr[1] + kc0);                                   \
    const char* gs_ = wt_bytes + (size_t)(s_) * 8192;                           \
    gload_lds16(gs_ + (size_t)(wv * 64 + lane) * 16,                            \
                (char*)&lds_w[bb_][0] + (size_t)(wv * 64) * 16);                \
    gload_lds16(gs_ + (size_t)(256 + wv * 64 + lane) * 16,                      \
                (char*)&lds_w[bb_][0] + (size_t)(256 + wv * 64) * 16);          \
  }

#define STAGE_STORE(bb_)                                                        \
  {                                                                             \
    union { short4v v; __hip_bfloat16 h[4]; } c0, c1;                           \
    c0.h[0] = __float2bfloat16(a_st0.x); c0.h[1] = __float2bfloat16(a_st0.y);   \
    c0.h[2] = __float2bfloat16(a_st0.z); c0.h[3] = __float2bfloat16(a_st0.w);   \
    c1.h[0] = __float2bfloat16(a_st1.x); c1.h[1] = __float2bfloat16(a_st1.y);   \
    c1.h[2] = __float2bfloat16(a_st1.z); c1.h[3] = __float2bfloat16(a_st1.w);   \
    *(short4v*)((char*)&lds_a[bb_][0] + a_woff[0]) = c0.v;                      \
    *(short4v*)((char*)&lds_a[bb_][0] + a_woff[1]) = c1.v;                      \
  }

  STAGE_LOAD(s0, 0);
  STAGE_STORE(0);
  __syncthreads();

  int bb = 0;
  for (int s = s0; s < s1; ++s) {
    const bool more = (s + 1 < s1);
    if (more) STAGE_LOAD(s + 1, bb ^ 1);

    const __hip_bfloat16* la = lds_a[bb];
    const __hip_bfloat16* lw = lds_w[bb];
    short8 afrag = *(const short8*)((const char*)la + a_roff);
#pragma unroll
    for (int mt = 0; mt < 8; ++mt) {
      short8 wfrag = *(const short8*)((const char*)lw + w_roff[mt]);
      acc[mt] = __builtin_amdgcn_mfma_f32_16x16x32_bf16(wfrag, afrag, acc[mt], 0, 0, 0);
    }

    if (more) STAGE_STORE(bb ^ 1);
    __syncthreads();
    bb ^= 1;
  }

  int r = row_g0 + wv * 16 + rloc;
  if (r < N) {
    float* dst = Cp + (size_t)(rowoff + r) * 128 + kg * 4;
#pragma unroll
    for (int mt = 0; mt < 8; ++mt)
      *(float4v*)(dst + mt * 16) = acc[mt];
  }
#undef STAGE_LOAD
#undef STAGE_STORE
}

// sum NP partials -> init (f32) + both state sections (bf16)
template<int NP>
__global__ __launch_bounds__(256) void combineN(
    P8 parr, float4v* __restrict__ o_init, __hip_bfloat16* __restrict__ state,
    int n4, int NtD)
{
  int i = blockIdx.x * 256 + threadIdx.x;
  if (i >= n4) return;
  float4v s = parr.p[0] ? ((const float4v*)parr.p[0])[i] : (float4v){0,0,0,0};
#pragma unroll
  for (int j = 1; j < NP; ++j) {
    float4v x = ((const float4v*)parr.p[j])[i];
    s.x += x.x; s.y += x.y; s.z += x.z; s.w += x.w;
  }
  o_init[i] = s;
  union { short4v v; __hip_bfloat16 h[4]; } b;
  b.h[0] = __float2bfloat16(s.x); b.h[1] = __float2bfloat16(s.y);
  b.h[2] = __float2bfloat16(s.z); b.h[3] = __float2bfloat16(s.w);
  *(short4v*)(state + (size_t)i * 4) = b.v;
  *(short4v*)(state + (size_t)NtD + (size_t)i * 4) = b.v;
}

// ---------------- unified gather (state in bf16), unrolled over P and L ----------------
template<int L, int PP>
__device__ __forceinline__ float gath(const __hip_bfloat16* __restrict__ sect,
                                      const int* __restrict__ paths,
                                      const float* __restrict__ pw, int n, int N, int d)
{
  float pwv[L];
#pragma unroll
  for (int l = 0; l < L; ++l) pwv[l] = pw[l * 128 + d];
  float acc = 0.f;
  const int* ip0 = paths + (size_t)n * L;
#pragma unroll
  for (int p = 0; p < PP; ++p) {
    const int* ip = ip0 + (size_t)p * N * L;   // wave-uniform -> scalar loads
    int idx[L];
#pragma unroll
    for (int l = 0; l < L; ++l) idx[l] = ip[l];
#pragma unroll
    for (int l = 0; l < L; ++l)
      acc = fmaf(pwv[l], __bfloat162float(sect[(size_t)idx[l] * 128 + d]), acc);
  }
  return acc;
}

template<int LMM, int LMD, int PP>
__global__ __launch_bounds__(256) void gather_all(
    const __hip_bfloat16* __restrict__ state,
    const int* __restrict__ paths_mm, const int* __restrict__ paths_dd, const int* __restrict__ paths_md,
    const float* __restrict__ pw1l, const float* __restrict__ pw2l,
    float* __restrict__ r, int Nm, int Nd)
{
  const int d = threadIdx.x & 127;
  const int nsub = threadIdx.x >> 7;
  const int g = blockIdx.x * 2 + nsub;
  const int Nt = Nm + Nd;
  if (g >= 2 * Nt) return;
  float acc;
  if (g < Nm)
    acc = gath<LMM, PP>(state, paths_mm, pw1l, g, Nm, d);
  else if (g < Nt)
    acc = gath<LMM, PP>(state + (size_t)Nm * 128, paths_dd, pw1l, g - Nm, Nd, d);
  else
    acc = gath<LMD, PP>(state + (size_t)Nt * 128, paths_md, pw2l, g - Nt, Nt, d);
  r[(size_t)g * 128 + d] = acc * (1.0f / (float)PP);
}

// runtime fallback
__global__ __launch_bounds__(256) void gather_einsum_rt(
    const __hip_bfloat16* __restrict__ feats, const int* __restrict__ paths,
    const float* __restrict__ pw, float* __restrict__ r, int N, int P, int L)
{
  const int d = threadIdx.x & 127;
  const int n = blockIdx.x * 2 + (threadIdx.x >> 7);
  if (n >= N) return;
  float acc = 0.f;
  for (int p = 0; p < P; ++p) {
    const int* ip = paths + ((size_t)p * N + n) * L;
    for (int l = 0; l < L; ++l)
      acc = fmaf(pw[l * 128 + d], __bfloat162float(feats[(size_t)ip[l] * 128 + d]), acc);
  }
  r[(size_t)n * 128 + d] = acc * (1.0f / (float)P);
}

// ---------------- fc layer: K=128, writes state as bf16 ----------------
template<int TR>
__global__ __launch_bounds__(256) void fc_all(
    const float* __restrict__ Rm, const float* __restrict__ W,
    const float* __restrict__ initb, __hip_bfloat16* __restrict__ state, int Ntot, int Nt)
{
  const int col = threadIdx.x & 127;
  const int rh  = __builtin_amdgcn_readfirstlane((int)(threadIdx.x >> 7));
  const int row0 = blockIdx.x * (2 * TR) + rh * TR;
  const float* arow[TR];
#pragma unroll
  for (int r = 0; r < TR; ++r) {
    int rr = row0 + r; if (rr > Ntot - 1) rr = Ntot - 1;
    arow[r] = Rm + (size_t)rr * 128;
  }
  float acc[TR];
#pragma unroll
  for (int r = 0; r < TR; ++r) acc[r] = 0.f;
#pragma unroll 4
  for (int k = 0; k < 128; k += 8) {
    float w[8];
#pragma unroll
    for (int kk = 0; kk < 8; ++kk) w[kk] = W[(size_t)(k + kk) * 128 + col];
#pragma unroll
    for (int r = 0; r < TR; ++r) {
      const float* ap = arow[r] + k;
#pragma unroll
      for (int kk = 0; kk < 8; ++kk) acc[r] = fmaf(ap[kk], w[kk], acc[r]);
    }
  }
#pragma unroll
  for (int r = 0; r < TR; ++r) {
    int rr = row0 + r;
    if (rr < Ntot) {
      int rbase = (rr < Nt) ? rr : rr - Nt;
      float v = ALPHA_ * initb[(size_t)rbase * 128 + col] + (1.f - ALPHA_) * fmaxf(acc[r], 0.f);
      state[(size_t)rr * 128 + col] = __float2bfloat16(v);
    }
  }
}

// MLP collapse (ILP-4)
__global__ void collapse1(const float* __restrict__ W0, const float* __restrict__ b0,
                          const float* __restrict__ W1, const float* __restrict__ b1,
                          float* __restrict__ w01, float* __restrict__ b01,
                          int E, int K0, int H1)
{
  int row = blockIdx.x; int c = threadIdx.x;
  if (c >= H1) return;
  const float* src; float base;
  if (row < E) { src = W0 + (size_t)row * K0; base = 0.f; }
  else         { src = b0; base = b1[c]; }
  float a0 = 0.f, a1 = 0.f, a2 = 0.f, a3 = 0.f;
#pragma unroll 4
  for (int k = 0; k < K0; k += 4) {
    a0 = fmaf(src[k + 0], W1[(size_t)(k + 0) * H1 + c], a0);
    a1 = fmaf(src[k + 1], W1[(size_t)(k + 1) * H1 + c], a1);
    a2 = fmaf(src[k + 2], W1[(size_t)(k + 2) * H1 + c], a2);
    a3 = fmaf(src[k + 3], W1[(size_t)(k + 3) * H1 + c], a3);
  }
  float acc = base + ((a0 + a1) + (a2 + a3));
  if (row < E) w01[(size_t)row * H1 + c] = acc; else b01[c] = acc;
}

__global__ void collapse2(const float* __restrict__ w01, const float* __restrict__ b01,
                          const float* __restrict__ W2, const float* __restrict__ b2,
                          float* __restrict__ w512, float* __restrict__ csc,
                          int E, int H1)
{
  int i = blockIdx.x * blockDim.x + threadIdx.x;
  if (i < E) {
    float a0 = 0.f, a1 = 0.f, a2 = 0.f, a3 = 0.f;
    for (int j = 0; j < H1; j += 4) {
      a0 = fmaf(w01[(size_t)i * H1 + j + 0], W2[j + 0], a0);
      a1 = fmaf(w01[(size_t)i * H1 + j + 1], W2[j + 1], a1);
      a2 = fmaf(w01[(size_t)i * H1 + j + 2], W2[j + 2], a2);
      a3 = fmaf(w01[(size_t)i * H1 + j + 3], W2[j + 3], a3);
    }
    w512[i] = (a0 + a1) + (a2 + a3);
  } else if (i == E) {
    float a = b2[0];
    for (int j = 0; j < H1; ++j) a = fmaf(b01[j], W2[j], a);
    csc[0] = a;
  }
}

__global__ __launch_bounds__(256) void node_partial(
    const __hip_bfloat16* __restrict__ Fmm, const __hip_bfloat16* __restrict__ Fdd,
    const __hip_bfloat16* __restrict__ Fmd,
    const float* __restrict__ w512, float* __restrict__ uv, int Nm, int Nt)
{
  int gid = blockIdx.x * blockDim.x + threadIdx.x;
  int wid = gid >> 6;
  int lane = threadIdx.x & 63;
  if (wid >= Nt) return;
  bool isM = wid < Nm;
  const __hip_bfloat16* X = isM ? (Fmm + (size_t)wid * 128) : (Fdd + (size_t)(wid - Nm) * 128);
  const __hip_bfloat16* Y = Fmd + (size_t)wid * 128;
  const float* w1 = w512 + (isM ? 0 : 256);
  const float* w2 = w1 + 128;
  float s = __bfloat162float(X[lane]) * w1[lane];
  s = fmaf(__bfloat162float(X[lane + 64]), w1[lane + 64], s);
  s = fmaf(__bfloat162float(Y[lane]), w2[lane], s);
  s = fmaf(__bfloat162float(Y[lane + 64]), w2[lane + 64], s);
#pragma unroll
  for (int off = 32; off > 0; off >>= 1) s += __shfl_down(s, off);
  if (lane == 0) uv[wid] = s;
}

__global__ __launch_bounds__(256) void score_kernel(
    const int* __restrict__ samples, const float* __restrict__ u, const float* __restrict__ v,
    const float* __restrict__ csc, float* __restrict__ out, int S)
{
  int s = blockIdx.x * blockDim.x + threadIdx.x;
  if (s >= S) return;
  const int2 ij = ((const int2*)samples)[s];
  float x = u[ij.x] + v[ij.y] + csc[0];
  out[s] = 1.0f / (1.0f + expf(-x));
}

extern "C" void kernel_launch(void* const* d_in, const int* in_sizes, int n_in,
                              void* d_out, int out_size, void* d_ws, size_t ws_size,
                              hipStream_t stream)
{
  const int*   paths_mm = (const int*)d_in[0];
  const int*   paths_dd = (const int*)d_in[1];
  const int*   paths_md = (const int*)d_in[2];
  const float* miRNA    = (const float*)d_in[3];
  const float* disease  = (const float*)d_in[4];
  const int*   samples  = (const int*)d_in[5];
  const float* Wm  = (const float*)d_in[6];
  const float* Wd  = (const float*)d_in[7];
  const float* pw1 = (const float*)d_in[8];
  const float* pw2 = (const float*)d_in[9];
  const float* fcW = (const float*)d_in[10];
  const float* W0  = (const float*)d_in[11];
  const float* b0  = (const float*)d_in[12];
  const float* W1  = (const float*)d_in[13];
  const float* b1  = (const float*)d_in[14];
  const float* W2  = (const float*)d_in[15];
  const float* b2  = (const float*)d_in[16];

  const int D  = 128;
  const int Nm = in_sizes[6] / D;
  const int Nd = in_sizes[7] / D;
  const int Nt = Nm + Nd;
  const int S  = in_sizes[5] / 2;
  const int layers = in_sizes[10] / (D * D);
  const int L1 = in_sizes[8] / (layers * D);
  const int L2 = in_sizes[9] / (layers * D);
  const int P  = in_sizes[0] / (Nm * L1);
  const int E  = 4 * D;
  const int K0 = in_sizes[12];
  const int H1 = in_sizes[14];
  const int Kpm = cdiv(Nm, 32) * 32;   // 8000
  const int Kpd = cdiv(Nd, 32) * 32;   // 6016
  const size_t NtD = (size_t)Nt * D;

  float* out = (float*)d_out;
  float* ws  = (float*)d_ws;
  size_t off = 0;
  float* init  = ws + off; off += NtD;                       // f32 summed init
  __hip_bfloat16* state = (__hip_bfloat16*)(ws + off); off += NtD;  // 2*NtD bf16
  float* bufR  = ws + off; off += 2 * NtD;                   // gather output (f32)
  float* w01   = ws + off; off += (size_t)E * H1;
  float* b01   = ws + off; off += H1;
  float* w512  = ws + off; off += E;
  float* csc   = ws + off; off += 1;
  float* uv    = ws + off; off += Nt;
  __hip_bfloat16* WtTm = (__hip_bfloat16*)(ws + off); off += (size_t)D * Kpm / 2;
  __hip_bfloat16* WtTd = (__hip_bfloat16*)(ws + off); off += (size_t)D * Kpd / 2;
  float* pextra = ws + off;
  const bool big_ws = (off + 5 * NtD) * 4 <= ws_size;
  (void)n_in; (void)out_size;

  // 1. tile-major bf16 weight transposes
  make_wtT<<<Kpm / 32, 256, 0, stream>>>(Wm, WtTm, Nm);
  make_wtT<<<Kpd / 32, 256, 0, stream>>>(Wd, WtTd, Nd);

  // 2. MLP collapse
  collapse1<<<E + 1, 64, 0, stream>>>(W0, b0, W1, b1, w01, b01, E, K0, H1);
  collapse2<<<cdiv(E + 1, 256), 256, 0, stream>>>(w01, b01, W2, b2, w512, csc, E, H1);

  // 3. init GEMMs
  {
    int nbm = cdiv(Nm, 64), nbd = cdiv(Nd, 64);
    int n4 = (int)(NtD / 4);
    P8 parr;
    parr.p[0] = init;
    parr.p[1] = bufR;
    parr.p[2] = bufR + NtD;
    if (big_ws) {
      for (int j = 0; j < 5; ++j) parr.p[3 + j] = pextra + (size_t)j * NtD;
      init_mfma2<8><<<(nbm + nbd) * 8, 256, 0, stream>>>(
          miRNA, WtTm, Nm, nbm, disease, WtTd, Nd, Kpd, parr);
      combineN<8><<<cdiv(n4, 256), 256, 0, stream>>>(parr, (float4v*)init, state, n4, (int)NtD);
    } else {
      for (int j = 3; j < 8; ++j) parr.p[j] = nullptr;
      init_mfma2<3><<<(nbm + nbd) * 3, 256, 0, stream>>>(
          miRNA, WtTm, Nm, nbm, disease, WtTd, Nd, Kpd, parr);
      combineN<3><<<cdiv(n4, 256), 256, 0, stream>>>(parr, (float4v*)init, state, n4, (int)NtD);
    }
  }

  // 4. fused path-layer chains (state bf16, residual from f32 init)
  constexpr int TR = 8;
  for (int l = 0; l < layers; ++l) {
    const float* pw1l = pw1 + (size_t)l * L1 * D;
    const float* pw2l = pw2 + (size_t)l * L2 * D;
    if (L1 == 4 && L2 == 6 && P == 8) {
      gather_all<4, 6, 8><<<Nt, 256, 0, stream>>>(
          state, paths_mm, paths_dd, paths_md, pw1l, pw2l, bufR, Nm, Nd);
    } else {
      gather_einsum_rt<<<cdiv(Nm, 2), 256, 0, stream>>>(state, paths_mm, pw1l, bufR, Nm, P, L1);
      gather_einsum_rt<<<cdiv(Nd, 2), 256, 0, stream>>>(state + (size_t)Nm * D, paths_dd, pw1l,
                                                        bufR + (size_t)Nm * D, Nd, P, L2 == L1 ? L1 : L1);
      gather_einsum_rt<<<cdiv(Nt, 2), 256, 0, stream>>>(state + NtD, paths_md, pw2l,
                                                        bufR + NtD, Nt, P, L2);
    }
    fc_all<TR><<<cdiv(2 * Nt, 2 * TR), 256, 0, stream>>>(
        bufR, fcW + (size_t)l * D * D, init, state, 2 * Nt, Nt);
  }

  // 5. per-node partial dots + scoring
  node_partial<<<cdiv(Nt * 64, 256), 256, 0, stream>>>(
      state, state + (size_t)Nm * D, state + NtD, w512, uv, Nm, Nt);
  score_kernel<<<cdiv(S, 256), 256, 0, stream>>>(samples, uv, uv + Nm, csc, out, S);
}